// Round 7
// baseline (299.160 us; speedup 1.0000x reference)
//
#include <hip/hip_runtime.h>

#define BATCH   64
#define CHANS   36
#define ANCH    8400
#define NCLS    32
#define MAXDET  100
#define CONF    0.25f
#define KTOP    512             // matrix region (bucket-aligned cutoff K <= KTOP)
#define NBUCK   2048
#define BUCK0   (0x3E800000u >> 13)   // bucket base: 8192-ulp buckets over [0.25,1.0)
#define PBLK    9               // prep blocks per image (ceil(2100/256))

typedef unsigned long long u64;
typedef unsigned int       u32;

// exact ref IoU-threshold compare: for uni>0, RN(inter/uni) > 0.45f <=> inter > M*uni
// (a = suppressor box, matching reference op order; f32 ops, no contraction)
__device__ __forceinline__ bool iou_gt(float ay1, float ax1, float ay2, float ax2, float aar,
                                       float by1, float bx1, float by2, float bx2, float bar,
                                       double M) {
#pragma clang fp contract(off)
    float iy1 = fmaxf(ay1, by1), ix1 = fmaxf(ax1, bx1);
    float iy2 = fminf(ay2, by2), ix2 = fminf(ax2, bx2);
    float inter = fmaxf(iy2 - iy1, 0.f) * fmaxf(ix2 - ix1, 0.f);
    float uni = (aar + bar) - inter;
    return (double)inter > M * (double)uni;
}

// recompute clipped corner box for anchor a (bit-identical to reference:
// same ops, same order, contract off)
__device__ __forceinline__ float4 load_box(const float* __restrict__ inb, int a) {
#pragma clang fp contract(off)
    float xc = inb[0 * ANCH + a], yc = inb[1 * ANCH + a];
    float w  = inb[2 * ANCH + a], h  = inb[3 * ANCH + a];
    float4 r;
    r.x = fminf(fmaxf(yc - h * 0.5f, 0.f), 1.f);
    r.y = fminf(fmaxf(xc - w * 0.5f, 0.f), 1.f);
    r.z = fminf(fmaxf(yc + h * 0.5f, 0.f), 1.f);
    r.w = fminf(fmaxf(xc + w * 0.5f, 0.f), 1.f);
    return r;
}

// ---------------- Phase A: keys + per-block histogram partials ----------------
// No box writes (recomputed downstream), no global atomics, no memset needed:
// block (bx,b) plain-stores its full 2048-entry LDS histogram slice.
__global__ __launch_bounds__(256) void yolo_prep(const float* __restrict__ in,
                                                 u64* __restrict__ wk64,
                                                 u32* __restrict__ histp) {
#pragma clang fp contract(off)
    const int G = ANCH / 4;             // 2100
    int g = blockIdx.x * 256 + threadIdx.x;
    int b = blockIdx.y;

    __shared__ u32 lh[NBUCK];
    for (int i = threadIdx.x; i < NBUCK; i += 256) lh[i] = 0u;
    __syncthreads();

    if (g < G) {
        const float4* p = (const float4*)(in + (size_t)b * (CHANS * ANCH));
        float4 best = p[4 * G + g];
        uint4 bc = make_uint4(0, 0, 0, 0);
#pragma unroll
        for (int k = 1; k < NCLS; ++k) {
            float4 v = p[(4 + k) * G + g];
            if (v.x > best.x) { best.x = v.x; bc.x = k; }   // strict >: first index (np.argmax)
            if (v.y > best.y) { best.y = v.y; bc.y = k; }
            if (v.z > best.z) { best.z = v.z; bc.z = k; }
            if (v.w > best.w) { best.w = v.w; bc.w = k; }
        }
        u64* wk = wk64 + (size_t)b * ANCH + 4 * g;
#define PREP_C(C, I)                                                          \
        {                                                                     \
            u64 kv = 0ull;                                                    \
            if (best.C >= CONF) {                                             \
                u32 sb = __float_as_uint(best.C);                             \
                kv = ((u64)sb << 32) |                                        \
                     ((u64)(16383 - (4 * g + I)) << 18) | (u64)(bc.C & 31u);  \
                atomicAdd(&lh[(sb >> 13) - BUCK0], 1u);                       \
            }                                                                 \
            wk[I] = kv;                                                       \
        }
        PREP_C(x, 0) PREP_C(y, 1) PREP_C(z, 2) PREP_C(w, 3)
#undef PREP_C
    }
    __syncthreads();
    u32* gh = histp + ((size_t)b * PBLK + blockIdx.x) * NBUCK;
    for (int i = threadIdx.x; i < NBUCK; i += 256) gh[i] = lh[i];
}

// ---------------- Phase B: fused threshold + matrix + fixpoint + emit ----------------
// Per image (64 blocks x 256): sum hist partials -> bucket-aligned taub with
// K = count(bucket >= taub) <= KTOP; compact A-keys; gather/recompute A-boxes;
// build the KxK suppression-bit matrix IN LDS; ballot fixpoint (exact greedy);
// rank-emit. Bucket alignment => A is suppression-closed (exactness). Rare
// continuation over sub-threshold keys preserved (exact for any density).
__global__ __launch_bounds__(256) void yolo_nms(const float* __restrict__ in,
                                                u64* __restrict__ wk64,
                                                const u32* __restrict__ histp,
                                                float* __restrict__ out) {
#pragma clang fp contract(off)
    const double M = (double)0.45f + 0x1p-26;
    int b = blockIdx.x, t = threadIdx.x;
    const float* inb = in + (size_t)b * (CHANS * ANCH);
    u64* gk = wk64 + (size_t)b * ANCH;

    __shared__ u32    hist[NBUCK];       // 8 KB
    __shared__ u64    ck[KTOP];          // 4 KB
    __shared__ float4 cb[KTOP];          // 8 KB
    __shared__ float  ca[KTOP];          // 2 KB
    __shared__ u64    SP[KTOP * 9];      // 36.9 KB (9-stride pad)
    __shared__ u64    selKey[KTOP];      // 4 KB
    __shared__ float  selb[MAXDET][5];   // 2 KB
    __shared__ u64    redm[4];
    __shared__ u32    wsum[4];
    __shared__ u32    bestP, shT, curA, staub, shK;
    __shared__ int    selTotS;

    float* outBox = out + (size_t)b * (MAXDET * 4);
    float* outCls = out + (size_t)(BATCH * MAXDET * 4) + b * MAXDET;
    float* outScr = out + (size_t)(BATCH * MAXDET * 5) + b * MAXDET;
    float* outNum = out + (size_t)(BATCH * MAXDET * 6) + b;

    if (t == 0) { bestP = 0u; curA = 0u; }

    // ---- sum the 9 per-block histogram partials ----
    const u32* ghp = histp + (size_t)b * PBLK * NBUCK;
    for (int i = t; i < NBUCK; i += 256) {
        u32 c = 0;
#pragma unroll
        for (int j = 0; j < PBLK; ++j) c += ghp[j * NBUCK + i];
        hist[i] = c;
    }
    __syncthreads();

    // ---- scan (rank r = bucket 2047-r, score-descending); pick taub/K/T ----
    u32 c8[8], sloc[8];
    u32 run = 0;
#pragma unroll
    for (int q = 0; q < 8; ++q) {
        int r = t * 8 + q;
        c8[q] = hist[2047 - r];
        run += c8[q];
        sloc[q] = run;
    }
    u32 Su = run;
    u32 x = Su;
#pragma unroll
    for (int d = 1; d < 64; d <<= 1) {
        u32 y = __shfl_up(x, d, 64);
        if ((t & 63) >= d) x += y;
    }
    if ((t & 63) == 63) wsum[t >> 6] = x;
    __syncthreads();
    u32 base = 0;
    for (int w = 0; w < (t >> 6); ++w) base += wsum[w];
    u32 excl = base + x - Su;            // exclusive prefix (by rank) of my group

    u32 mypk = 0;                        // largest inclusive boundary <= KTOP
#pragma unroll
    for (int q = 0; q < 8; ++q) {
        u32 inc = excl + sloc[q];
        if (inc <= (u32)KTOP) {
            u32 pk = (inc << 11) | (u32)(t * 8 + q);
            if (pk > mypk) mypk = pk;
        }
    }
    if (mypk) atomicMax(&bestP, mypk);
    if (t == 255) shT = excl + Su;
    __syncthreads();
    if (t == 0) {
        u32 bp = bestP;
        if (bp == 0u) { shK = 0u; staub = (u32)NBUCK; }
        else { shK = bp >> 11; staub = 2047u - (bp & 0x7FFu); }
    }
    __syncthreads();
    u32 taub = staub;
    int K = (int)shK, T = (int)shT;

    // ---- compact A-keys (unsorted; keys carry the total order) ----
    for (int j = 0; j < 33; ++j) {
        int a = t + j * 256;
        if (a < ANCH) {
            u64 k = gk[a];
            if (k != 0ull && ((u32)(k >> 45) - BUCK0) >= taub) {
                u32 slot = atomicAdd(&curA, 1u);
                if (slot < (u32)KTOP) ck[slot] = k;   // slot < K by construction; clamp defensively
            }
        }
    }
    __syncthreads();
    for (int i = K + t; i < KTOP; i += 256) ck[i] = 0ull;
    __syncthreads();

    // ---- gather/recompute A-boxes ----
    for (int i = t; i < KTOP; i += 256) {
        u64 k = ck[i];
        float4 bb = make_float4(0.f, 0.f, 0.f, 0.f);
        if (k != 0ull) {
            int a = 16383 - (int)((k >> 18) & 0x3FFFull);
            bb = load_box(inb, a);
        }
        cb[i] = bb;
        ca[i] = (bb.z - bb.x) * (bb.w - bb.y);
    }
    __syncthreads();

    // ---- suppression-bit matrix in LDS: rows t and t+256 ----
#pragma unroll
    for (int rr = 0; rr < 2; ++rr) {
        int row = t + rr * 256;
        u64 kr = ck[row];
        float4 rb = cb[row];
        float rar = ca[row];
#pragma unroll
        for (int w = 0; w < 8; ++w) {
            u64 word = 0ull;
            int base0 = w << 6;
#pragma unroll 4
            for (int j2 = 0; j2 < 64; ++j2) {
                int i = base0 + j2;
                u64 ki = ck[i];               // broadcast reads (conflict-free)
                if ((ki > kr) && iou_gt(cb[i].x, cb[i].y, cb[i].z, cb[i].w, ca[i],
                                        rb.x, rb.y, rb.z, rb.w, rar, M))
                    word |= 1ull << j2;
            }
            SP[row * 9 + w] = word;
        }
    }
    __syncthreads();

    // ---- ballot fixpoint over top-K (wave 0; exact greedy) ----
    u64 S[8];
#pragma unroll
    for (int w = 0; w < 8; ++w) S[w] = 0ull;
    if (t < 64) {
        int L = t;
        u64 U[8];
#pragma unroll
        for (int w = 0; w < 8; ++w) U[w] = __ballot(ck[(w << 6) + L] != 0ull);
        for (int it = 0; it < KTOP; ++it) {
            if (!(U[0] | U[1] | U[2] | U[3] | U[4] | U[5] | U[6] | U[7])) break;
            u64 D[8];
#pragma unroll
            for (int w = 0; w < 8; ++w) {
                const u64* rm = &SP[((w << 6) + L) * 9];
                u64 pend = (rm[0] & U[0]) | (rm[1] & U[1]) | (rm[2] & U[2]) | (rm[3] & U[3])
                         | (rm[4] & U[4]) | (rm[5] & U[5]) | (rm[6] & U[6]) | (rm[7] & U[7]);
                D[w] = __ballot(((U[w] >> L) & 1ull) && (pend == 0ull));
            }
#pragma unroll
            for (int w = 0; w < 8; ++w) { S[w] |= D[w]; U[w] &= ~D[w]; }
#pragma unroll
            for (int w = 0; w < 8; ++w) {
                const u64* rm = &SP[((w << 6) + L) * 9];
                u64 hit = (rm[0] & D[0]) | (rm[1] & D[1]) | (rm[2] & D[2]) | (rm[3] & D[3])
                        | (rm[4] & D[4]) | (rm[5] & D[5]) | (rm[6] & D[6]) | (rm[7] & D[7]);
                U[w] &= ~__ballot(((U[w] >> L) & 1ull) && (hit != 0ull));
            }
        }
        if (t == 0) {
            int c = 0;
#pragma unroll
            for (int w = 0; w < 8; ++w) c += (int)__popcll(S[w]);
            selTotS = c;
        }
    }
    __syncthreads();

    // ---- dense selected-key list (slot order; ranking is by key) ----
    if (t < 64) {
        int L = t, kbase = 0;
#pragma unroll
        for (int w = 0; w < 8; ++w) {
            u64 Sw = S[w];
            if ((Sw >> L) & 1ull) {
                int r = kbase + (int)__popcll(Sw & ((1ull << L) - 1ull));
                selKey[r] = ck[(w << 6) + L];
            }
            kbase += (int)__popcll(Sw);
        }
    }
    __syncthreads();

    int sTot = selTotS;
    int s = sTot < MAXDET ? sTot : MAXDET;

    // ---- emission in exact key order (parallel rank-by-count) ----
    if (t < 64) {
        int L = t;
#pragma unroll
        for (int w = 0; w < 8; ++w) {
            if ((S[w] >> L) & 1ull) {
                u64 myk = ck[(w << 6) + L];
                int pos = 0;
                for (int j = 0; j < sTot; ++j) pos += (selKey[j] > myk) ? 1 : 0;
                if (pos < MAXDET) {
                    int a = 16383 - (int)((myk >> 18) & 0x3FFFull);
                    float4 bb = load_box(inb, a);
                    outScr[pos] = __uint_as_float((u32)(myk >> 32));
                    outCls[pos] = (float)((u32)myk & 31u);
                    outBox[pos * 4 + 0] = bb.x; outBox[pos * 4 + 1] = bb.y;
                    outBox[pos * 4 + 2] = bb.z; outBox[pos * 4 + 3] = bb.w;
                    selb[pos][0] = bb.x; selb[pos][1] = bb.y; selb[pos][2] = bb.z;
                    selb[pos][3] = bb.w; selb[pos][4] = (bb.z - bb.x) * (bb.w - bb.y);
                }
            }
        }
    }
    __syncthreads();

    // ---- exact continuation over sub-threshold keys (rare path) ----
    if (s < MAXDET && T > K) {
        for (int i = t; i < ANCH; i += 256) {    // de-dup A + prekill vs selected
            u64 k = gk[i];
            if (k != 0ull) {
                if (((u32)(k >> 45) - BUCK0) >= taub) { gk[i] = 0ull; continue; }
                int a = 16383 - (int)((k >> 18) & 0x3FFFull);
                float4 bb = load_box(inb, a);
                float ar = (bb.z - bb.x) * (bb.w - bb.y);
                for (int j = 0; j < s; ++j) {
                    if (iou_gt(selb[j][0], selb[j][1], selb[j][2], selb[j][3], selb[j][4],
                               bb.x, bb.y, bb.z, bb.w, ar, M)) { gk[i] = 0ull; break; }
                }
            }
        }
        __syncthreads();
        while (s < MAXDET) {
            u64 best = 0ull;
            for (int i = t; i < ANCH; i += 256) { u64 k = gk[i]; if (k > best) best = k; }
#pragma unroll
            for (int sh = 1; sh < 64; sh <<= 1) {
                u64 o = __shfl_xor(best, sh, 64);
                if (o > best) best = o;
            }
            if ((t & 63) == 0) redm[t >> 6] = best;
            __syncthreads();
            best = redm[0];
            for (int w = 1; w < 4; ++w) if (redm[w] > best) best = redm[w];
            if (best == 0ull) break;
            int a = 16383 - (int)((best >> 18) & 0x3FFFull);
            float4 nb = load_box(inb, a);
            float nar = (nb.z - nb.x) * (nb.w - nb.y);
            if (t == 0) {
                outScr[s] = __uint_as_float((u32)(best >> 32));
                outCls[s] = (float)((u32)best & 31u);
                outBox[s * 4 + 0] = nb.x; outBox[s * 4 + 1] = nb.y;
                outBox[s * 4 + 2] = nb.z; outBox[s * 4 + 3] = nb.w;
            }
            for (int i = t; i < ANCH; i += 256) {
                u64 k = gk[i];
                if (k != 0ull) {
                    if (k == best) gk[i] = 0ull;
                    else {
                        int a2 = 16383 - (int)((k >> 18) & 0x3FFFull);
                        float4 bb = load_box(inb, a2);
                        float ar = (bb.z - bb.x) * (bb.w - bb.y);
                        if (iou_gt(nb.x, nb.y, nb.z, nb.w, nar,
                                   bb.x, bb.y, bb.z, bb.w, ar, M)) gk[i] = 0ull;
                    }
                }
            }
            ++s;
            __syncthreads();
        }
    }

    for (int q = s + t; q < MAXDET; q += 256) {
        outScr[q] = 0.f; outCls[q] = 0.f;
        outBox[q * 4 + 0] = 0.f; outBox[q * 4 + 1] = 0.f;
        outBox[q * 4 + 2] = 0.f; outBox[q * 4 + 3] = 0.f;
    }
    if (t == 0) *outNum = (float)s;
}

extern "C" void kernel_launch(void* const* d_in, const int* in_sizes, int n_in,
                              void* d_out, int out_size, void* d_ws, size_t ws_size,
                              hipStream_t stream) {
    const float* in = (const float*)d_in[0];
    float* out = (float*)d_out;
    // workspace layout (~9 MB):
    //   wk64  u64[64*8400]               4,300,800 B
    //   histp u32[64*9*2048]             4,718,592 B  (per-block partials, fully
    //                                                  overwritten each launch)
    char* w = (char*)d_ws;
    u64* wk64  = (u64*)w;
    u32* histp = (u32*)(w + 4300800);

    yolo_prep<<<dim3(PBLK, BATCH), 256, 0, stream>>>(in, wk64, histp);
    yolo_nms<<<BATCH, 256, 0, stream>>>(in, wk64, histp, out);
}